// Round 6
// baseline (475.809 us; speedup 1.0000x reference)
//
#include <hip/hip_runtime.h>
#include <hip/hip_bf16.h>

#define NB 32
#define NN 1000
#define COMD 64
#define HIDD 256
#define KSEL 500
#define TI 16        // dst rows per k_gat block
#define GATX ((NN + TI - 1) / TI)  // 63 gat x-blocks
#define NSPL 32      // n-splits for k_psum
#define ROWS 32      // ceil(NN/NSPL)
#define DSTRIDE 1024 // padded distT row stride

// k_prep role bases (adjacency is now read directly by the GAT kernels).
#define PB_DT   0                    // 256 dist-transpose tiles
#define PB_WP   256                  // 40 blocks x 4 rows = 160 Wp rows
#define PB_WCO  296                  // 24 blocks x 4 rows = 96 Wco rows
#define PB_MISC 320                  // flags, wd, bias dots
#define PB_EMB  321                  // 8000 embed blocks (4 nodes each)
#define PB_N    (PB_EMB + NB * NN / 4)

typedef __hip_bfloat16 bf16;
typedef unsigned long long u64;
typedef __attribute__((ext_vector_type(4))) float f32x4;
typedef __attribute__((ext_vector_type(8))) short s16x8;
typedef __attribute__((ext_vector_type(4))) short s16x4;
typedef __attribute__((ext_vector_type(4))) unsigned short u16x4;

__device__ __forceinline__ float b2f(bf16 x){ return __bfloat162float(x); }

template<bool F32>
__device__ __forceinline__ float ldf(const void* p, long i){
  return F32 ? ((const float*)p)[i] : b2f(((const bf16*)p)[i]);
}
// runtime-flag variant (uniform scalar branch)
__device__ __forceinline__ float ldr(const void* p, long i, int f32){
  return f32 ? ((const float*)p)[i] : b2f(((const bf16*)p)[i]);
}
template<bool BINT>
__device__ __forceinline__ bool ldb(const void* p, long i){
  return BINT ? (((const int*)p)[i] != 0) : (((const unsigned char*)p)[i] != 0);
}

__device__ __forceinline__ float wave_sum(float v){
#pragma unroll
  for (int o = 32; o > 0; o >>= 1) v += __shfl_down(v, o, 64);
  return v;
}
__device__ __forceinline__ float wave_bsum(float v){
#pragma unroll
  for (int o = 32; o > 0; o >>= 1) v += __shfl_xor(v, o, 64);
  return v;
}
__device__ __forceinline__ float wave_bmax(float v){
#pragma unroll
  for (int o = 32; o > 0; o >>= 1) v = fmaxf(v, __shfl_xor(v, o, 64));
  return v;
}
__device__ __forceinline__ int wave_bsum_i(int v){
#pragma unroll
  for (int o = 32; o > 0; o >>= 1) v += __shfl_xor(v, o, 64);
  return v;
}
__device__ __forceinline__ unsigned fkey(float f){
  unsigned u = __float_as_uint(f);
  return (u & 0x80000000u) ? ~u : (u | 0x80000000u);
}
// split fp32 into bf16 hi + bf16 lo with v ≈ hi + lo (residual ~2^-16 rel)
__device__ __forceinline__ void split_bf(float v, short& hi, short& lo){
  unsigned u = __float_as_uint(v);
  float hf = __uint_as_float(u & 0xFFFF0000u);
  hi = (short)(u >> 16);
  float r = v - hf;                 // exact
  lo = (short)(__float_as_uint(r) >> 16);
}
__device__ __forceinline__ short f2bs(float v){
  bf16 h = __float2bfloat16(v);
  short s; __builtin_memcpy(&s, &h, 2); return s;
}
__device__ __forceinline__ void hB_write(short* hB_hi, short* hB_lo,
                                         int b, int n, int ch, float v){
  int kb = n >> 5, g4 = (n >> 3) & 3, u = n & 7;
  long off = ((((long)b * 32 + kb) * 4 + g4) * 64 + ch) * 8 + u;
  short hi, lo; split_bf(v, hi, lo);
  hB_hi[off] = hi; hB_lo[off] = lo;
}
// cheap per-block dtype sniff: 2 loads + 2 ballots
__device__ __forceinline__ void sniff2(const void* dist, const void* adjc,
                                       int lane, int& f32, int& as_int){
  unsigned wdist = ((const unsigned*)dist)[lane];
  unsigned wadj  = ((const unsigned*)adjc)[lane];
  f32 = (__ballot((wdist & 0xFFFFu) >= 0x8000u) != 0ull) ? 1 : 0;
  as_int = (__ballot(wadj > 1u) == 0ull) ? 1 : 0;
}

// ================ roles ================
#define SMEM_BYTES 8704

template<bool F32>
__device__ __forceinline__ void dist_t_role(const void* dist, bf16* distTb,
                                            int rel, void* sm){
  bf16 (*tile)[68] = (bf16 (*)[68])sm;
  int t = threadIdx.x;
  int wv = t >> 6, lane = t & 63;
  int it = (rel & 15) * 64, jt = (rel >> 4) * 64;
#pragma unroll
  for (int r = 0; r < 16; ++r){
    int jl = r * 4 + wv;
    int j = jt + jl, i = it + lane;
    float v = (j < NN && i < NN) ? ldf<F32>(dist, (long)j * NN + i) : 0.f;
    tile[jl][lane] = __float2bfloat16(v);
  }
  __syncthreads();
#pragma unroll
  for (int r = 0; r < 16; ++r){
    int il = r * 4 + wv;
    int i = it + il, j = jt + lane;
    if (i < NN) distTb[(long)i * DSTRIDE + j] = tile[lane][il];
  }
}
template<bool F32>
__device__ __forceinline__ void wp_role(const void* Wp, const void* vpd, const void* vpf,
                        short* WpB_hi, short* WpB_lo, float* wv_ws, int rel){
  int t = threadIdx.x;
  int g = t >> 6, lane = t & 63;
  int f = rel * 4 + g;               // 0..159
  float wrow[4];
#pragma unroll
  for (int r = 0; r < 4; ++r){
    int ch = r * 64 + lane;
    wrow[r] = (f < 147) ? ldf<F32>(Wp, (long)f * HIDD + ch) : 0.f;
  }
  int kb = f >> 5, q = (f >> 3) & 3, u = f & 7;
#pragma unroll
  for (int r = 0; r < 4; ++r){
    int ch = r * 64 + lane;
    long off = (((long)(kb * 4 + q)) * 256 + ch) * 8 + u;
    short hi, lo; split_bf(wrow[r], hi, lo);
    WpB_hi[off] = hi; WpB_lo[off] = lo;
  }
  float ad = 0.f, af = 0.f;
#pragma unroll
  for (int r = 0; r < 4; ++r){
    int ch = r * 64 + lane;
    ad += wrow[r] * ldf<F32>(vpd, ch);
    af += wrow[r] * ldf<F32>(vpf, ch);
  }
  ad = wave_bsum(ad); af = wave_bsum(af);
  if (lane == 0){ wv_ws[f] = ad; wv_ws[160 + f] = af; }
}
template<bool F32>
__device__ __forceinline__ void wco_role(const void* Wco, const void* asrc, const void* adst,
                         short* WcoB_hi, short* WcoB_lo, float* pvco, int rel){
  int t = threadIdx.x;
  int g = t >> 6, lane = t & 63;
  int f = rel * 4 + g;               // 0..95
  float w = (f < 79) ? ldf<F32>(Wco, (long)f * COMD + lane) : 0.f;
  int kb = f >> 5, q = (f >> 3) & 3, u = f & 7;
  long off = (((long)(kb * 4 + q)) * 64 + lane) * 8 + u;
  short hi, lo; split_bf(w, hi, lo);
  WcoB_hi[off] = hi; WcoB_lo[off] = lo;
  float dd = wave_bsum(w * ldf<F32>(adst, lane));
  float ss = wave_bsum(w * ldf<F32>(asrc, lane));
  if (lane == 0){ pvco[f] = dd; pvco[96 + f] = ss; }
}
template<bool F32>
__device__ __forceinline__ void misc_role(const void* wdc, const void* wdco,
                          const void* bp, const void* vpd, const void* vpf,
                          int f32, int as_int,
                          int* flags, float* wd_ws, float* wv_ws){
  int t = threadIdx.x;
  if (t >= 64) return;
  int lane = t;
  float ad = 0.f, af = 0.f;
#pragma unroll
  for (int r = 0; r < 4; ++r){
    int ch = r * 64 + lane;
    float bb = ldf<F32>(bp, ch);
    ad += bb * ldf<F32>(vpd, ch);
    af += bb * ldf<F32>(vpf, ch);
  }
  ad = wave_bsum(ad); af = wave_bsum(af);
  if (lane == 0){
    wv_ws[320] = ad; wv_ws[321] = af;
    wd_ws[0] = ldf<F32>(wdc, 0);
    wd_ws[1] = ldf<F32>(wdco, 0);
    flags[0] = f32; flags[1] = as_int;
  }
}
// embedding + h_c (direct to hB planes) + attn scalars
template<bool F32>
__device__ __forceinline__ void embed_body(
    const int* op_idx, const void* vf, const void* cs_tab, const void* tp_tab,
    const void* Wc, const void* asrc, const void* adst,
    float* x_out, short* hB_hi, short* hB_lo, float* ed_out, float* es_out,
    int rel){
  int t = threadIdx.x;
  int w = t >> 6, lane = t & 63;
  int g = rel * 4 + w;
  int b = g / NN, n = g - b * NN;
  int op = op_idx[g];
  float xv = 0.f, hacc = 0.f;
#pragma unroll
  for (int f = 0; f < 15; ++f){
    float x_f;
    if (f < 4)      x_f = ldf<F32>(cs_tab, n * 4 + f);
    else if (f < 6) x_f = ldf<F32>(tp_tab, op * 2 + (f - 4));
    else            x_f = ldf<F32>(vf, (long)g * 9 + (f - 6));
    if (lane == f) xv = x_f;
    hacc += x_f * ldf<F32>(Wc, f * COMD + lane);
  }
  if (lane < 15) x_out[g * 15 + lane] = xv;
  hB_write(hB_hi, hB_lo, b, n, lane, hacc);
  float sd = wave_sum(hacc * ldf<F32>(adst, lane));
  float ss = wave_sum(hacc * ldf<F32>(asrc, lane));
  if (lane == 0){ ed_out[g] = sd; es_out[g] = ss; }
}
__global__ void __launch_bounds__(256) k_prep(
    const void* dist, const void* adj_comp,
    const void* wdc, const void* wdco,
    const void* Wp, const void* vpd, const void* vpf, const void* bp,
    const void* Wco, const void* asrc_co, const void* adst_co,
    const int* op_idx, const void* vfeat, const void* cs_tab, const void* tp_tab,
    const void* Wc, const void* asrc_c, const void* adst_c,
    int* flags, float* wd_ws, bf16* distTb,
    short* WpB_hi, short* WpB_lo, float* wv_ws,
    short* WcoB_hi, short* WcoB_lo, float* pvco,
    float* x_ws, short* hB_hi, short* hB_lo, float* ed_c, float* es_c){
  __shared__ __attribute__((aligned(16))) char smem[SMEM_BYTES];
  int blk = blockIdx.x;
  int f32, as_int;
  sniff2(dist, adj_comp, threadIdx.x & 63, f32, as_int);
  if (blk < PB_WP){
    if (f32) dist_t_role<true >(dist, distTb, blk - PB_DT, smem);
    else     dist_t_role<false>(dist, distTb, blk - PB_DT, smem);
  } else if (blk < PB_WCO){
    if (f32) wp_role<true >(Wp, vpd, vpf, WpB_hi, WpB_lo, wv_ws, blk - PB_WP);
    else     wp_role<false>(Wp, vpd, vpf, WpB_hi, WpB_lo, wv_ws, blk - PB_WP);
  } else if (blk < PB_MISC){
    if (f32) wco_role<true >(Wco, asrc_co, adst_co, WcoB_hi, WcoB_lo, pvco, blk - PB_WCO);
    else     wco_role<false>(Wco, asrc_co, adst_co, WcoB_hi, WcoB_lo, pvco, blk - PB_WCO);
  } else if (blk < PB_EMB){
    if (f32) misc_role<true >(wdc, wdco, bp, vpd, vpf, f32, as_int, flags, wd_ws, wv_ws);
    else     misc_role<false>(wdc, wdco, bp, vpd, vpf, f32, as_int, flags, wd_ws, wv_ws);
  } else {
    if (f32) embed_body<true >(op_idx, vfeat, cs_tab, tp_tab, Wc, asrc_c, adst_c,
                               x_ws, hB_hi, hB_lo, ed_c, es_c, blk - PB_EMB);
    else     embed_body<false>(op_idx, vfeat, cs_tab, tp_tab, Wc, asrc_c, adst_c,
                               x_ws, hB_hi, hB_lo, ed_c, es_c, blk - PB_EMB);
  }
}

// ---------------- masked-softmax GAT with fused epilogues ----------------
// Adjacency is read DIRECTLY from the input (no packed adjQ): each block needs
// adj[b][j][i0..i0+16) — one aligned 64B line (int32) / 16B (bytes) per row j,
// fully consumed, so HBM efficiency is unchanged while the entire pack
// infrastructure (128 MB stream in k_prep + pack blocks + adjQ buffers)
// disappears. Tail tile clamps the window to ib=NN-16 and shifts bit
// extraction by sh=i0-ib; rows past NN get bit 0 -> p=0 (discarded anyway);
// j>=NN keeps mask 0 so softmax sums are exact.
// MODE 0 (gat1): writes comp reps; fused h_co epilogue -> hB2 + ed_o/es_o.
// MODE 1 (gat2x): coop reps stay in registers; fused x_p epilogue.
template<int MODE>
__device__ __forceinline__ void gat_body(
    const float* __restrict__ ed, const float* __restrict__ es,
    const float* __restrict__ wd_ws, int wd_idx,
    const bf16* __restrict__ distTb,
    const short* __restrict__ hB_hi, const short* __restrict__ hB_lo,
    float* __restrict__ reps,
    const int* __restrict__ flags, const void* __restrict__ adj_raw,
    const float* __restrict__ x_ws,
    const short* __restrict__ WcoB_hi, const short* __restrict__ WcoB_lo,
    const float* __restrict__ pvco,
    short* hB2_hi, short* hB2_lo, float* ed_o, float* es_o,
    // MODE 1 extras:
    const int* __restrict__ time_idx, const int* __restrict__ op_idx,
    const void* vf, const void* time_tab, const void* cs_tab, const void* tp_tab,
    const float* __restrict__ comp,
    const short* __restrict__ WpB_hi, const short* __restrict__ WpB_lo,
    const float* __restrict__ wv_ws, const void* bp,
    float* x_p, float* scf_o, float* scd_o){
  __shared__ short pA[32 * 544] __attribute__((aligned(16)));
  __shared__ float redz[TI][4];
  __shared__ float esred[4];
  int t = threadIdx.x;
  int wv = t >> 6, lane = t & 63;
  int b = blockIdx.y;
  int i0 = blockIdx.x * TI;
  float wd = wd_ws[wd_idx];
  int j0 = t * 4;

  // ---- direct adjacency mask: am[c] bit k = adj[b][j0+c][ib+k] != 0 ----
  unsigned am[4];
  int ib = (i0 + 16 <= NN) ? i0 : (NN - 16);
  int sh = i0 - ib;                 // 0 except last tile (8)
  {
    int bint = flags[1];
    if (bint){
      const int* abase = (const int*)adj_raw + ((long)b * NN) * NN + ib;
#pragma unroll
      for (int c = 0; c < 4; ++c){
        int j = j0 + c;
        unsigned m = 0u;
        if (j < NN){
          const int* rp = abase + (long)j * NN;   // 16B-aligned (1000*4, ib*4 % 16 == 0)
          uint4 d0 = *(const uint4*)(rp + 0);
          uint4 d1 = *(const uint4*)(rp + 4);
          uint4 d2 = *(const uint4*)(rp + 8);
          uint4 d3 = *(const uint4*)(rp + 12);
          m = (unsigned)(d0.x != 0)        | ((unsigned)(d0.y != 0) << 1)
            | ((unsigned)(d0.z != 0) << 2) | ((unsigned)(d0.w != 0) << 3)
            | ((unsigned)(d1.x != 0) << 4) | ((unsigned)(d1.y != 0) << 5)
            | ((unsigned)(d1.z != 0) << 6) | ((unsigned)(d1.w != 0) << 7)
            | ((unsigned)(d2.x != 0) << 8) | ((unsigned)(d2.y != 0) << 9)
            | ((unsigned)(d2.z != 0) << 10)| ((unsigned)(d2.w != 0) << 11)
            | ((unsigned)(d3.x != 0) << 12)| ((unsigned)(d3.y != 0) << 13)
            | ((unsigned)(d3.z != 0) << 14)| ((unsigned)(d3.w != 0) << 15);
        }
        am[c] = m;
      }
    } else {
      const unsigned char* abase = (const unsigned char*)adj_raw + (long)b * NN * NN + ib;
#pragma unroll
      for (int c = 0; c < 4; ++c){
        int j = j0 + c;
        unsigned m = 0u;
        if (j < NN){
          const u64* rp = (const u64*)(abase + (long)j * NN);  // 8B-aligned
          u64 w0 = rp[0], w1 = rp[1];
#pragma unroll
          for (int k = 0; k < 8; ++k){
            m |= (unsigned)(((w0 >> (8 * k)) & 0xFFull) != 0) << k;
            m |= (unsigned)(((w1 >> (8 * k)) & 0xFFull) != 0) << (k + 8);
          }
        }
        am[c] = m;
      }
    }
  }

  float4 es4 = *(const float4*)&es[(long)b * NN + j0];
  float esv[4] = {es4.x, es4.y, es4.z, es4.w};
  float esm = -1e30f;
#pragma unroll
  for (int c = 0; c < 4; ++c)
    esm = fmaxf(esm, (j0 + c < NN) ? esv[c] : -1e30f);
  esm = wave_bmax(esm);
  if (lane == 0) esred[wv] = esm;

  float ed_i[TI]; float edm = -1e30f;
#pragma unroll
  for (int ti = 0; ti < TI; ++ti){
    int i = i0 + ti;
    float ev = ed[(long)b * NN + ((i < NN) ? i : (NN - 1))];
    ed_i[ti] = ev;
    edm = fmaxf(edm, (i < NN) ? ev : -1e30f);
  }
  __syncthreads();
  float M = fmaxf(fmaxf(esred[0], esred[1]), fmaxf(esred[2], esred[3]))
            + edm + fmaxf(wd, 0.f);
  M = fmaxf(M, 0.f);   // uniform upper bound on all scores; softmax exact

  float p[TI][4];
  const bf16* dbase = distTb + j0;
#pragma unroll
  for (int ti = 0; ti < TI; ++ti){
    int i = i0 + ti;
    int ic = (i < NN) ? i : (NN - 1);
    u16x4 d4 = *(const u16x4*)&dbase[(long)ic * DSTRIDE];
    float edti = ed_i[ti];
    int kbit = ti + sh;                       // >=16 on discarded tail rows -> 0
#pragma unroll
    for (int c = 0; c < 4; ++c){
      float d = __uint_as_float((unsigned)d4[c] << 16);
      float v = edti + esv[c] + wd * d;
      v = fmaxf(v, 0.2f * v);                 // leaky_relu
      bool edge = (am[c] >> kbit) & 1u;
      float e = edge ? v : -1e30f;
      p[ti][c] = __expf(e - M);
    }
  }

  int kbw = 8 * wv + (lane >> 3);
  int qw = (lane >> 1) & 3;
  int u0 = 4 * (lane & 1);
  int wbase = kbw * 544 + qw * 136 + u0;
#pragma unroll
  for (int ti = 0; ti < TI; ++ti){
    float zs = p[ti][0] + p[ti][1] + p[ti][2] + p[ti][3];
    zs = wave_bsum(zs);
    if (lane == 0) redz[ti][wv] = zs;
    s16x4 s4 = { f2bs(p[ti][0]), f2bs(p[ti][1]), f2bs(p[ti][2]), f2bs(p[ti][3]) };
    *(s16x4*)&pA[wbase + ti * 8] = s4;
  }
  __syncthreads();

  int q = lane >> 4, m = lane & 15;
  int abase = q * 136 + m * 8;
  int ch = wv * 16 + m;
  const short* bh = hB_hi + (long)b * 65536 + ((long)q * 64 + ch) * 8;
  const short* bl = hB_lo + (long)b * 65536 + ((long)q * 64 + ch) * 8;
  f32x4 acc = {0.f, 0.f, 0.f, 0.f};
#pragma unroll
  for (int kb = 0; kb < 32; ++kb){
    s16x8 a   = *(const s16x8*)&pA[kb * 544 + abase];
    s16x8 bhi = *(const s16x8*)&bh[(long)kb * 2048];
    s16x8 blo = *(const s16x8*)&bl[(long)kb * 2048];
    acc = __builtin_amdgcn_mfma_f32_16x16x32_bf16(a, bhi, acc, 0, 0, 0);
    acc = __builtin_amdgcn_mfma_f32_16x16x32_bf16(a, blo, acc, 0, 0, 0);
  }
  float vr[4];
#pragma unroll
  for (int reg = 0; reg < 4; ++reg){
    int ti = (lane >> 4) * 4 + reg;
    float z = redz[ti][0] + redz[ti][1] + redz[ti][2] + redz[ti][3];
    float zi = (z > 0.f) ? 1.f / z : 0.f;
    float v = acc[reg] * zi;
    v = (v > 0.f) ? v : expm1f(v);
    vr[reg] = v;
    if (MODE == 0){
      int ch2 = wv * 16 + (lane & 15);
      if (i0 + ti < NN)
        reps[((long)b * NN + i0 + ti) * COMD + ch2] = v;
    }
  }

  if (MODE == 0){
    // ---- fused h_co epilogue (replaces k_hco), overlaying pA's LDS ----
    __syncthreads();                 // all pA reads done; safe to overwrite
    float* cx = (float*)pA;          // [16][80] fp32, 5120 B
    short* cA_hi = pA + 2560;        // 3*16*40 shorts
    short* cA_lo = pA + 2560 + 1920;
    {
      int ch2 = wv * 16 + (lane & 15);
#pragma unroll
      for (int reg = 0; reg < 4; ++reg){
        int row = (lane >> 4) * 4 + reg;
        cx[row * 80 + 15 + ch2] = vr[reg];
      }
    }
    for (int idx = t; idx < 16 * 15; idx += 256){
      int nl = idx / 15, f = idx - nl * 15;
      int i = i0 + nl; int ic = (i < NN) ? i : (NN - 1);
      cx[nl * 80 + f] = x_ws[((long)b * NN + ic) * 15 + f];
    }
    __syncthreads();
    {
      int node = t >> 4, sub = t & 15;
      float dd = 0.f, ss = 0.f;
      for (int f = sub; f < 79; f += 16){
        float c = cx[node * 80 + f];
        dd += c * pvco[f];
        ss += c * pvco[96 + f];
      }
#pragma unroll
      for (int o = 8; o > 0; o >>= 1){
        dd += __shfl_xor(dd, o, 64);
        ss += __shfl_xor(ss, o, 64);
      }
      if (sub == 0 && i0 + node < NN){
        ed_o[(long)b * NN + i0 + node] = dd;
        es_o[(long)b * NN + i0 + node] = ss;
      }
    }
    for (int idx = t; idx < 16 * 96; idx += 256){
      int mm = idx / 96, k = idx - mm * 96;
      float v = (k < 79) ? cx[mm * 80 + k] : 0.f;
      int kb = k >> 5, qq = (k >> 3) & 3, u = k & 7;
      short hi, lo; split_bf(v, hi, lo);
      int off = (kb * 16 + mm) * 40 + qq * 8 + u;
      cA_hi[off] = hi; cA_lo[off] = lo;
    }
    __syncthreads();
    {
      int q2 = lane >> 4, m2 = lane & 15;
      int ch3 = wv * 16 + m2;
      f32x4 a2 = {0.f, 0.f, 0.f, 0.f};
#pragma unroll
      for (int kb = 0; kb < 3; ++kb){
        int aoff = (kb * 16 + m2) * 40 + q2 * 8;
        s16x8 a_hi = *(const s16x8*)&cA_hi[aoff];
        s16x8 a_lo = *(const s16x8*)&cA_lo[aoff];
        long boff = (((long)(kb * 4 + q2)) * 64 + ch3) * 8;
        s16x8 b_hi = *(const s16x8*)&WcoB_hi[boff];
        s16x8 b_lo = *(const s16x8*)&WcoB_lo[boff];
        a2 = __builtin_amdgcn_mfma_f32_16x16x32_bf16(a_hi, b_hi, a2, 0, 0, 0);
        a2 = __builtin_amdgcn_mfma_f32_16x16x32_bf16(a_hi, b_lo, a2, 0, 0, 0);
        a2 = __builtin_amdgcn_mfma_f32_16x16x32_bf16(a_lo, b_hi, a2, 0, 0, 0);
      }
#pragma unroll
      for (int reg = 0; reg < 4; ++reg){
        int row = (lane >> 4) * 4 + reg;
        int n2 = i0 + row;                 // n<1024 slots exist; tail unread
        hB_write(hB2_hi, hB2_lo, b, n2, ch3, a2[reg]);
      }
    }
  } else {
    // ---- fused x_p epilogue (replaces k_xp), overlaying pA's LDS ----
    __syncthreads();                 // all pA reads done; safe to overwrite
    float* sagF = (float*)pA;        // [16][148] fp32 = 9472 B
    short* sgA_hi = pA + 4736;       // 5*16*40 shorts = 6400 B
    short* sgA_lo = pA + 7936;       // 5*16*40 shorts
    int f32 = flags[0];
    {
      int ch2 = wv * 16 + (lane & 15);
#pragma unroll
      for (int reg = 0; reg < 4; ++reg){
        int row = (lane >> 4) * 4 + reg;
        sagF[row * 148 + 83 + ch2] = vr[reg];   // coop from registers
      }
    }
    for (int idx = t; idx < 16 * 83; idx += 256){
      int nl = idx / 83, f = idx - nl * 83;
      int n = i0 + nl; int ic = (n < NN) ? n : (NN - 1);
      long g = (long)b * NN + ic;
      float v;
      if (f < 4)       v = ldr(time_tab, (long)time_idx[g] * 4 + f, f32);
      else if (f < 8)  v = ldr(cs_tab, ic * 4 + (f - 4), f32);
      else if (f < 10) v = ldr(tp_tab, (long)op_idx[g] * 2 + (f - 8), f32);
      else if (f < 19) v = ldr(vf, g * 9 + (f - 10), f32);
      else             v = comp[g * COMD + (f - 19)];
      sagF[nl * 148 + f] = v;
    }
    __syncthreads();
    for (int idx = t; idx < 16 * 160; idx += 256){
      int mm = idx / 160, k = idx - mm * 160;
      float v = (k < 147) ? sagF[mm * 148 + k] : 0.f;
      int kb = k >> 5, qq = (k >> 3) & 3, u = k & 7;
      short hi, lo; split_bf(v, hi, lo);
      int off = (kb * 16 + mm) * 40 + qq * 8 + u;
      sgA_hi[off] = hi; sgA_lo[off] = lo;
    }
    {
      int node = t >> 4, sub = t & 15;
      float ad = 0.f, af = 0.f;
      for (int f = sub; f < 147; f += 16){
        float s = sagF[node * 148 + f];
        ad += s * wv_ws[f];
        af += s * wv_ws[160 + f];
      }
#pragma unroll
      for (int o = 8; o > 0; o >>= 1){
        ad += __shfl_xor(ad, o, 64);
        af += __shfl_xor(af, o, 64);
      }
      if (sub == 0 && i0 + node < NN){
        scd_o[(long)b * NN + i0 + node] = ad + wv_ws[320];
        scf_o[(long)b * NN + i0 + node] = af + wv_ws[321];
      }
    }
    __syncthreads();
    int Ag = lane >> 4, Am = lane & 15;
    f32x4 acc2[4] = {{0,0,0,0},{0,0,0,0},{0,0,0,0},{0,0,0,0}};
#pragma unroll
    for (int kb = 0; kb < 5; ++kb){
      int aoff = (kb * 16 + Am) * 40 + Ag * 8;
      s16x8 a_hi = *(const s16x8*)&sgA_hi[aoff];
      s16x8 a_lo = *(const s16x8*)&sgA_lo[aoff];
#pragma unroll
      for (int ct = 0; ct < 4; ++ct){
        int ch3 = wv * 64 + ct * 16 + Am;
        long boff = (((long)(kb * 4 + Ag)) * 256 + ch3) * 8;
        s16x8 b_hi = *(const s16x8*)&WpB_hi[boff];
        s16x8 b_lo = *(const s16x8*)&WpB_lo[boff];
        acc2[ct] = __builtin_amdgcn_mfma_f32_16x16x32_bf16(a_hi, b_hi, acc2[ct], 0, 0, 0);
        acc2[ct] = __builtin_amdgcn_mfma_f32_16x16x32_bf16(a_hi, b_lo, acc2[ct], 0, 0, 0);
        acc2[ct] = __builtin_amdgcn_mfma_f32_16x16x32_bf16(a_lo, b_hi, acc2[ct], 0, 0, 0);
      }
    }
#pragma unroll
    for (int ct = 0; ct < 4; ++ct){
      int ch3 = wv * 64 + ct * 16 + (lane & 15);
      float bb = ldr(bp, ch3, f32);
#pragma unroll
      for (int reg = 0; reg < 4; ++reg){
        int row = (lane >> 4) * 4 + reg;
        if (i0 + row < NN)
          x_p[((long)b * NN + i0 + row) * HIDD + ch3] = acc2[ct][reg] + bb;
      }
    }
  }
}
__global__ void __launch_bounds__(256) k_gat1(
    const float* ed, const float* es, const float* wd_ws,
    const bf16* distTb, const short* hB_hi, const short* hB_lo, float* reps,
    const int* flags, const void* adj_raw,
    const float* x_ws, const short* WcoB_hi, const short* WcoB_lo,
    const float* pvco, short* hB2_hi, short* hB2_lo, float* ed_o, float* es_o){
  gat_body<0>(ed, es, wd_ws, 0, distTb, hB_hi, hB_lo, reps,
              flags, adj_raw, x_ws, WcoB_hi, WcoB_lo, pvco,
              hB2_hi, hB2_lo, ed_o, es_o,
              nullptr, nullptr, nullptr, nullptr, nullptr, nullptr,
              nullptr, nullptr, nullptr, nullptr, nullptr,
              nullptr, nullptr, nullptr);
}
__global__ void __launch_bounds__(256) k_gat2x(
    const float* ed, const float* es, const float* wd_ws,
    const bf16* distTb, const short* hB_hi, const short* hB_lo,
    const int* flags, const void* adj_raw,
    const int* time_idx, const int* op_idx, const void* vf,
    const void* time_tab, const void* cs_tab, const void* tp_tab,
    const float* comp, const short* WpB_hi, const short* WpB_lo,
    const float* wv_ws, const void* bp,
    float* x_p, float* scf, float* scd){
  gat_body<1>(ed, es, wd_ws, 1, distTb, hB_hi, hB_lo, nullptr,
              flags, adj_raw, nullptr, nullptr, nullptr, nullptr,
              nullptr, nullptr, nullptr, nullptr,
              time_idx, op_idx, vf, time_tab, cs_tab, tp_tab,
              comp, WpB_hi, WpB_lo, wv_ws, bp, x_p, scf, scd);
}

// ---------------- top-k weights: one wave per (b,pool) ----------------
template<bool BINT>
__device__ __forceinline__ void topk_body(
    const float* scf, const float* scd, const void* mark, float* wls){
  int lane = threadIdx.x;
  int b = blockIdx.x, pool = blockIdx.y;
  const float* sc = (pool == 0) ? scf : scd;
  float v[16]; unsigned key[16];
  float m0 = -INFINITY;
#pragma unroll
  for (int r = 0; r < 16; ++r){
    int n = r * 64 + lane;
    float s = (n < NN) ? sc[b * NN + n] : -INFINITY;
    v[r] = s;
    m0 = fmaxf(m0, s);
  }
  m0 = wave_bmax(m0);
  float m1 = -INFINITY;
#pragma unroll
  for (int r = 0; r < 16; ++r){
    int n = r * 64 + lane;
    bool valid = false;
    if (n < NN){
      bool mk = ldb<BINT>(mark, b * NN + n);
      valid = (pool == 0) ? !mk : mk;
    }
    v[r] = valid ? (v[r] - m0) : -1e8f;
    key[r] = fkey(v[r]);
    if (n < NN) m1 = fmaxf(m1, v[r]);
  }
  m1 = wave_bmax(m1);

  unsigned lo = 0u, hi = 0xFFFFFFFFu;
  while (lo < hi){
    unsigned mid = lo + ((hi - lo) >> 1) + 1u;
    int c = 0;
#pragma unroll
    for (int r = 0; r < 16; ++r) c += (key[r] >= mid) ? 1 : 0;
    c = wave_bsum_i(c);
    if (c >= KSEL) lo = mid; else hi = mid - 1u;
  }

  float p[16];
  float ls = 0.f;
#pragma unroll
  for (int r = 0; r < 16; ++r){
    int n = r * 64 + lane;
    float pp = (n < NN && key[r] >= lo) ? __expf(v[r] - m1) : 0.f;
    p[r] = pp;
    ls += pp;
  }
  ls = wave_bsum(ls);
  float zinv = (ls > 0.f) ? 1.f / ls : 0.f;
  float* w_out = wls + ((long)b * 2 + pool) * 1024;
#pragma unroll
  for (int r = 0; r < 16; ++r){
    int n = r * 64 + lane;
    if (n < NN) w_out[n] = p[r] * zinv;
  }
}
__global__ void k_topk(const int* flags, const float* scf, const float* scd,
                       const void* mark, float* wls){
  if (flags[1]) topk_body<true >(scf, scd, mark, wls);
  else          topk_body<false>(scf, scd, mark, wls);
}

// ---------------- gated partial sums ----------------
__global__ void __launch_bounds__(256) k_psum(
    const float* __restrict__ wls, const float* __restrict__ x_p,
    float* __restrict__ part){
  __shared__ float wf[ROWS], wdd[ROWS];
  int t = threadIdx.x;
  int b = blockIdx.x, z = blockIdx.y;
  int n0 = z * ROWS;
  int ns = min(ROWS, NN - n0);
  if (t < ns){
    wf[t]  = wls[((long)b * 2 + 0) * 1024 + n0 + t];
    wdd[t] = wls[((long)b * 2 + 1) * 1024 + n0 + t];
  }
  __syncthreads();
  float sf = 0.f, mf = -INFINITY, sd = 0.f, md = -INFINITY;
  const float* xb = x_p + ((long)b * NN + n0) * HIDD + t;
  for (int k = 0; k < ns; ++k){
    float xv = xb[(long)k * HIDD];
    float gf = wf[k] * xv;
    float gd = wdd[k] * xv;
    sf += gf; mf = fmaxf(mf, gf);
    sd += gd; md = fmaxf(md, gd);
  }
  long pb = (((long)b * NSPL + z) * 4) * HIDD + t;
  part[pb + 0 * HIDD] = sf;
  part[pb + 1 * HIDD] = mf;
  part[pb + 2 * HIDD] = sd;
  part[pb + 3 * HIDD] = md;
}

// ---------------- final reduce ----------------
template<bool F32>
__device__ __forceinline__ void pfin_body(const float* part, void* out){
  int t = threadIdx.x;
  int b = blockIdx.x;
  float sf = 0.f, mf = -INFINITY, sd = 0.f, md = -INFINITY;
#pragma unroll
  for (int z = 0; z < NSPL; ++z){
    long pb = (((long)b * NSPL + z) * 4) * HIDD + t;
    sf += part[pb + 0 * HIDD];
    mf = fmaxf(mf, part[pb + 1 * HIDD]);
    sd += part[pb + 2 * HIDD];
    md = fmaxf(md, part[pb + 3 * HIDD]);
  }
  long ob = (long)b * 1024;
  if (F32){
    ((float*)out)[ob + t] = sf;
    ((float*)out)[ob + 256 + t] = mf;
    ((float*)out)[ob + 512 + t] = sd;
    ((float*)out)[ob + 768 + t] = md;
  } else {
    ((bf16*)out)[ob + t] = __float2bfloat16(sf);
    ((bf16*)out)[ob + 256 + t] = __float2bfloat16(mf);
    ((bf16*)out)[ob + 512 + t] = __float2bfloat16(sd);
    ((bf16*)out)[ob + 768 + t] = __float2bfloat16(md);
  }
}
__global__ void k_pfin(const int* flags, const float* part, void* out){
  if (flags[0]) pfin_body<true >(part, out);
  else          pfin_body<false>(part, out);
}

extern "C" void kernel_launch(void* const* d_in, const int* in_sizes, int n_in,
                              void* d_out, int out_size, void* d_ws, size_t ws_size,
                              hipStream_t stream){
  const int*  time_idx = (const int*)d_in[0];
  const int*  op_idx   = (const int*)d_in[1];
  const void* vfeat    = d_in[2];
  const void* dpcs     = d_in[3];
  const void* adj_comp = d_in[4];
  const void* adj_coop = d_in[5];
  const void* dist     = d_in[6];
  const void* time_tab = d_in[7];
  const void* tp_tab   = d_in[8];
  const void* cs_tab   = d_in[9];
  const void* Wc       = d_in[10];
  const void* asrc_c   = d_in[11];
  const void* adst_c   = d_in[12];
  const void* wd_c     = d_in[13];
  const void* Wco      = d_in[14];
  const void* asrc_co  = d_in[15];
  const void* adst_co  = d_in[16];
  const void* wd_co    = d_in[17];
  const void* Wp       = d_in[18];
  const void* bp       = d_in[19];
  const void* vpd      = d_in[20];
  const void* vpf      = d_in[21];

  char* ws = (char*)d_ws;
  size_t o = 0;
  auto alloc = [&](size_t bytes)->char*{
    char* p = ws + o; o = (o + bytes + 255) & ~(size_t)255; return p;
  };
  int*   flags   = (int*)alloc(16);
  float* wd_ws   = (float*)alloc(8);
  bf16*  distTb  = (bf16*)alloc((size_t)NN * DSTRIDE * 2);
  float* x_ws    = (float*)alloc((size_t)NB * NN * 15 * 4);
  float* comp    = (float*)alloc((size_t)NB * NN * COMD * 4);
  short* hB_hi   = (short*)alloc((size_t)NB * 65536 * 2);
  short* hB_lo   = (short*)alloc((size_t)NB * 65536 * 2);
  short* hB2_hi  = (short*)alloc((size_t)NB * 65536 * 2);
  short* hB2_lo  = (short*)alloc((size_t)NB * 65536 * 2);
  short* WpB_hi  = (short*)alloc((size_t)5 * 4 * 256 * 8 * 2);
  short* WpB_lo  = (short*)alloc((size_t)5 * 4 * 256 * 8 * 2);
  short* WcoB_hi = (short*)alloc((size_t)3 * 4 * 64 * 8 * 2);
  short* WcoB_lo = (short*)alloc((size_t)3 * 4 * 64 * 8 * 2);
  float* wv_ws   = (float*)alloc(322 * 4);
  float* pvco    = (float*)alloc(192 * 4);
  float* ed_c    = (float*)alloc((size_t)NB * NN * 4 + 256);
  float* es_c    = (float*)alloc((size_t)NB * NN * 4 + 256);
  float* ed_o    = (float*)alloc((size_t)NB * NN * 4 + 256);
  float* es_o    = (float*)alloc((size_t)NB * NN * 4 + 256);
  float* scf     = (float*)alloc((size_t)NB * NN * 4);
  float* scd     = (float*)alloc((size_t)NB * NN * 4);
  float* wls     = (float*)alloc((size_t)NB * 2 * 1024 * 4);
  float* part    = (float*)alloc((size_t)NB * NSPL * 4 * HIDD * 4);
  float* x_p     = (float*)alloc((size_t)NB * NN * HIDD * 4);

  k_prep<<<dim3(PB_N), dim3(256), 0, stream>>>(
      dist, adj_comp, wd_c, wd_co, Wp, vpd, vpf, bp,
      Wco, asrc_co, adst_co,
      op_idx, vfeat, cs_tab, tp_tab, Wc, asrc_c, adst_c,
      flags, wd_ws, distTb, WpB_hi, WpB_lo, wv_ws,
      WcoB_hi, WcoB_lo, pvco,
      x_ws, hB_hi, hB_lo, ed_c, es_c);
  // gat#1: comp GAT (direct adj_comp read) + fused h_co epilogue
  k_gat1<<<dim3(GATX, NB), dim3(256), 0, stream>>>(
      ed_c, es_c, wd_ws, distTb, hB_hi, hB_lo, comp,
      flags, adj_comp,
      x_ws, WcoB_hi, WcoB_lo, pvco, hB2_hi, hB2_lo, ed_o, es_o);
  // gat#2: coop GAT (direct adj_coop read) + fused x_p/sag epilogue
  k_gat2x<<<dim3(GATX, NB), dim3(256), 0, stream>>>(
      ed_o, es_o, wd_ws, distTb, hB2_hi, hB2_lo,
      flags, adj_coop,
      time_idx, op_idx, vfeat, time_tab, cs_tab, tp_tab,
      comp, WpB_hi, WpB_lo, wv_ws, bp, x_p, scf, scd);
  // tail: kernel boundaries provide the ordering
  k_topk<<<dim3(NB, 2), dim3(64), 0, stream>>>(flags, scf, scd, dpcs, wls);
  k_psum<<<dim3(NB, NSPL), dim3(256), 0, stream>>>(wls, x_p, part);
  k_pfin<<<dim3(NB), dim3(256), 0, stream>>>(flags, part, d_out);
}

// Round 8
// 436.292 us; speedup vs baseline: 1.0906x; 1.0906x over previous
//
#include <hip/hip_runtime.h>
#include <hip/hip_bf16.h>

#define NB 32
#define NN 1000
#define COMD 64
#define HIDD 256
#define KSEL 500
#define TI 16        // dst rows per k_gat block
#define GATX ((NN + TI - 1) / TI)  // 63 gat x-blocks
#define PACKX 32     // extra x-blocks in k_gat#1 carrying adjQo pack (32*NB=1024)
#define NSPL 32      // n-splits for k_psum
#define ROWS 32      // ceil(NN/NSPL)
#define DSTRIDE 1024 // padded distT row stride

// k_prep role bases. adjQc (HBM-latency/BW-bound) first; adjQo is packed by
// k_gat#1's extra blocks, overlapping the comp-GAT compute.
#define PB_AQ1  0                    // 1024 adjq comp
#define PB_DT   1024                 // 256 dist-transpose tiles
#define PB_WP   1280                 // 40 blocks x 4 rows = 160 Wp rows
#define PB_WCO  1320                 // 24 blocks x 4 rows = 96 Wco rows
#define PB_MISC 1344                 // flags, wd, bias dots
#define PB_EMB  1345                 // 8000 embed blocks (4 nodes each)
#define PB_N    (PB_EMB + NB * NN / 4)

typedef __hip_bfloat16 bf16;
typedef unsigned long long u64;
typedef __attribute__((ext_vector_type(4))) float f32x4;
typedef __attribute__((ext_vector_type(8))) short s16x8;
typedef __attribute__((ext_vector_type(4))) short s16x4;
typedef __attribute__((ext_vector_type(4))) unsigned short u16x4;
typedef __attribute__((ext_vector_type(4))) unsigned int u32x4;
typedef __attribute__((ext_vector_type(2))) unsigned long long u64x2;

__device__ __forceinline__ float b2f(bf16 x){ return __bfloat162float(x); }

template<bool F32>
__device__ __forceinline__ float ldf(const void* p, long i){
  return F32 ? ((const float*)p)[i] : b2f(((const bf16*)p)[i]);
}
// runtime-flag variant (uniform scalar branch)
__device__ __forceinline__ float ldr(const void* p, long i, int f32){
  return f32 ? ((const float*)p)[i] : b2f(((const bf16*)p)[i]);
}
template<bool BINT>
__device__ __forceinline__ bool ldb(const void* p, long i){
  return BINT ? (((const int*)p)[i] != 0) : (((const unsigned char*)p)[i] != 0);
}

__device__ __forceinline__ float wave_sum(float v){
#pragma unroll
  for (int o = 32; o > 0; o >>= 1) v += __shfl_down(v, o, 64);
  return v;
}
__device__ __forceinline__ float wave_bsum(float v){
#pragma unroll
  for (int o = 32; o > 0; o >>= 1) v += __shfl_xor(v, o, 64);
  return v;
}
__device__ __forceinline__ float wave_bmax(float v){
#pragma unroll
  for (int o = 32; o > 0; o >>= 1) v = fmaxf(v, __shfl_xor(v, o, 64));
  return v;
}
__device__ __forceinline__ int wave_bsum_i(int v){
#pragma unroll
  for (int o = 32; o > 0; o >>= 1) v += __shfl_xor(v, o, 64);
  return v;
}
__device__ __forceinline__ unsigned fkey(float f){
  unsigned u = __float_as_uint(f);
  return (u & 0x80000000u) ? ~u : (u | 0x80000000u);
}
// split fp32 into bf16 hi + bf16 lo with v ≈ hi + lo (residual ~2^-16 rel)
__device__ __forceinline__ void split_bf(float v, short& hi, short& lo){
  unsigned u = __float_as_uint(v);
  float hf = __uint_as_float(u & 0xFFFF0000u);
  hi = (short)(u >> 16);
  float r = v - hf;                 // exact
  lo = (short)(__float_as_uint(r) >> 16);
}
__device__ __forceinline__ short f2bs(float v){
  bf16 h = __float2bfloat16(v);
  short s; __builtin_memcpy(&s, &h, 2); return s;
}
__device__ __forceinline__ void hB_write(short* hB_hi, short* hB_lo,
                                         int b, int n, int ch, float v){
  int kb = n >> 5, g4 = (n >> 3) & 3, u = n & 7;
  long off = ((((long)b * 32 + kb) * 4 + g4) * 64 + ch) * 8 + u;
  short hi, lo; split_bf(v, hi, lo);
  hB_hi[off] = hi; hB_lo[off] = lo;
}
// cheap per-block dtype sniff: 2 loads + 2 ballots
__device__ __forceinline__ void sniff2(const void* dist, const void* adjc,
                                       int lane, int& f32, int& as_int){
  unsigned wdist = ((const unsigned*)dist)[lane];
  unsigned wadj  = ((const unsigned*)adjc)[lane];
  f32 = (__ballot((wdist & 0xFFFFu) >= 0x8000u) != 0ull) ? 1 : 0;
  as_int = (__ballot(wadj > 1u) == 0ull) ? 1 : 0;
}

// ================ roles ================
#define SMEM_BYTES 8704

template<bool F32>
__device__ __forceinline__ void dist_t_role(const void* dist, bf16* distTb,
                                            int rel, void* sm){
  bf16 (*tile)[68] = (bf16 (*)[68])sm;
  int t = threadIdx.x;
  int wv = t >> 6, lane = t & 63;
  int it = (rel & 15) * 64, jt = (rel >> 4) * 64;
#pragma unroll
  for (int r = 0; r < 16; ++r){
    int jl = r * 4 + wv;
    int j = jt + jl, i = it + lane;
    float v = (j < NN && i < NN) ? ldf<F32>(dist, (long)j * NN + i) : 0.f;
    tile[jl][lane] = __float2bfloat16(v);
  }
  __syncthreads();
#pragma unroll
  for (int r = 0; r < 16; ++r){
    int il = r * 4 + wv;
    int i = it + il, j = jt + lane;
    if (i < NN) distTb[(long)i * DSTRIDE + j] = tile[lane][il];
  }
}
// adjacency pack: unconditional clamped loads + 2-row ping-pong prefetch.
// Adjacency is read-once: NONTEMPORAL loads keep the 128 MB stream from
// evicting re-read data (hB planes, distTb, adjQ) out of L2/L3.
// Words stored in PERMUTED bit order: bit p holds i-offset il with
// p = 16*(il&3) + (il>>2). j<NN word-zeroing keeps src-side garbage out.
template<bool BINT>
__device__ __forceinline__ void adjq_role(const void* adj, u64* adjQ,
                                          int rel, void* sm){
  u64 (*aw)[33] = (u64 (*)[33])sm;    // +1 pad
  int t = threadIdx.x;
  int wv = t >> 6, lane = t & 63;
  int j0 = (rel & 31) * 32;
  int b  = rel >> 5;
  int ch3 = (192 + lane < 250) ? (192 + lane) : 249;
  int chk[4] = { lane, 64 + lane, 128 + lane, ch3 };
  long row0;
  {
    int j = j0 + wv * 8;
    int jc = (j < NN) ? j : (NN - 1);
    row0 = ((long)b * NN + jc) * (long)NN;
  }
  if (BINT){
    const int* base = (const int*)adj;
    u32x4 cur[4], nxt[4];
#pragma unroll
    for (int c = 0; c < 4; ++c)
      cur[c] = __builtin_nontemporal_load((const u32x4*)(base + row0 + (long)chk[c] * 4));
#pragma unroll
    for (int r = 0; r < 8; ++r){
      if (r < 7){
        int j2 = j0 + wv * 8 + r + 1;
        int jc2 = (j2 < NN) ? j2 : (NN - 1);
        long row2 = ((long)b * NN + jc2) * (long)NN;
#pragma unroll
        for (int c = 0; c < 4; ++c)
          nxt[c] = __builtin_nontemporal_load((const u32x4*)(base + row2 + (long)chk[c] * 4));
      }
      int j = j0 + wv * 8 + r;
#pragma unroll
      for (int c = 0; c < 4; ++c){
        u64 bal0 = __ballot(cur[c][0] != 0u);
        u64 bal1 = __ballot(cur[c][1] != 0u);
        u64 bal2 = __ballot(cur[c][2] != 0u);
        u64 bal3 = __ballot(cur[c][3] != 0u);
        if (lane < 4){
          u64 w = 0;
          if (j < NN){
            int sh = 16 * lane;                // sub-word w' = lane
            w = ((bal0 >> sh) & 0xFFFFull)
              | (((bal1 >> sh) & 0xFFFFull) << 16)
              | (((bal2 >> sh) & 0xFFFFull) << 32)
              | (((bal3 >> sh) & 0xFFFFull) << 48);
          }
          aw[c * 4 + lane][wv * 8 + r] = w;    // iw = 4c + w'
        }
      }
      if (r < 7){
#pragma unroll
        for (int c = 0; c < 4; ++c) cur[c] = nxt[c];
      }
    }
  } else {
    const unsigned char* base = (const unsigned char*)adj;
    unsigned cur[4], nxt[4];
#pragma unroll
    for (int c = 0; c < 4; ++c)
      cur[c] = __builtin_nontemporal_load((const unsigned*)(base + row0 + (long)chk[c] * 4));
#pragma unroll
    for (int r = 0; r < 8; ++r){
      if (r < 7){
        int j2 = j0 + wv * 8 + r + 1;
        int jc2 = (j2 < NN) ? j2 : (NN - 1);
        long row2 = ((long)b * NN + jc2) * (long)NN;
#pragma unroll
        for (int c = 0; c < 4; ++c)
          nxt[c] = __builtin_nontemporal_load((const unsigned*)(base + row2 + (long)chk[c] * 4));
      }
      int j = j0 + wv * 8 + r;
#pragma unroll
      for (int c = 0; c < 4; ++c){
        u64 bal0 = __ballot((cur[c] & 0xFFu) != 0u);
        u64 bal1 = __ballot((cur[c] & 0xFF00u) != 0u);
        u64 bal2 = __ballot((cur[c] & 0xFF0000u) != 0u);
        u64 bal3 = __ballot((cur[c] & 0xFF000000u) != 0u);
        if (lane < 4){
          u64 w = 0;
          if (j < NN){
            int sh = 16 * lane;
            w = ((bal0 >> sh) & 0xFFFFull)
              | (((bal1 >> sh) & 0xFFFFull) << 16)
              | (((bal2 >> sh) & 0xFFFFull) << 32)
              | (((bal3 >> sh) & 0xFFFFull) << 48);
          }
          aw[c * 4 + lane][wv * 8 + r] = w;
        }
      }
      if (r < 7){
#pragma unroll
        for (int c = 0; c < 4; ++c) cur[c] = nxt[c];
      }
    }
  }
  __syncthreads();
#pragma unroll
  for (int rr = 0; rr < 2; ++rr){
    int w2 = t + rr * 256;
    int iw = w2 >> 5, jloc = w2 & 31;
    adjQ[((long)b * 16 + iw) * 1024 + j0 + jloc] = aw[iw][jloc];
  }
}
template<bool F32>
__device__ __forceinline__ void wp_role(const void* Wp, const void* vpd, const void* vpf,
                        short* WpB_hi, short* WpB_lo, float* wv_ws, int rel){
  int t = threadIdx.x;
  int g = t >> 6, lane = t & 63;
  int f = rel * 4 + g;               // 0..159
  float wrow[4];
#pragma unroll
  for (int r = 0; r < 4; ++r){
    int ch = r * 64 + lane;
    wrow[r] = (f < 147) ? ldf<F32>(Wp, (long)f * HIDD + ch) : 0.f;
  }
  int kb = f >> 5, q = (f >> 3) & 3, u = f & 7;
#pragma unroll
  for (int r = 0; r < 4; ++r){
    int ch = r * 64 + lane;
    long off = (((long)(kb * 4 + q)) * 256 + ch) * 8 + u;
    short hi, lo; split_bf(wrow[r], hi, lo);
    WpB_hi[off] = hi; WpB_lo[off] = lo;
  }
  float ad = 0.f, af = 0.f;
#pragma unroll
  for (int r = 0; r < 4; ++r){
    int ch = r * 64 + lane;
    ad += wrow[r] * ldf<F32>(vpd, ch);
    af += wrow[r] * ldf<F32>(vpf, ch);
  }
  ad = wave_bsum(ad); af = wave_bsum(af);
  if (lane == 0){ wv_ws[f] = ad; wv_ws[160 + f] = af; }
}
template<bool F32>
__device__ __forceinline__ void wco_role(const void* Wco, const void* asrc, const void* adst,
                         short* WcoB_hi, short* WcoB_lo, float* pvco, int rel){
  int t = threadIdx.x;
  int g = t >> 6, lane = t & 63;
  int f = rel * 4 + g;               // 0..95
  float w = (f < 79) ? ldf<F32>(Wco, (long)f * COMD + lane) : 0.f;
  int kb = f >> 5, q = (f >> 3) & 3, u = f & 7;
  long off = (((long)(kb * 4 + q)) * 64 + lane) * 8 + u;
  short hi, lo; split_bf(w, hi, lo);
  WcoB_hi[off] = hi; WcoB_lo[off] = lo;
  float dd = wave_bsum(w * ldf<F32>(adst, lane));
  float ss = wave_bsum(w * ldf<F32>(asrc, lane));
  if (lane == 0){ pvco[f] = dd; pvco[96 + f] = ss; }
}
template<bool F32>
__device__ __forceinline__ void misc_role(const void* wdc, const void* wdco,
                          const void* bp, const void* vpd, const void* vpf,
                          int f32, int as_int,
                          int* flags, float* wd_ws, float* wv_ws){
  int t = threadIdx.x;
  if (t >= 64) return;
  int lane = t;
  float ad = 0.f, af = 0.f;
#pragma unroll
  for (int r = 0; r < 4; ++r){
    int ch = r * 64 + lane;
    float bb = ldf<F32>(bp, ch);
    ad += bb * ldf<F32>(vpd, ch);
    af += bb * ldf<F32>(vpf, ch);
  }
  ad = wave_bsum(ad); af = wave_bsum(af);
  if (lane == 0){
    wv_ws[320] = ad; wv_ws[321] = af;
    wd_ws[0] = ldf<F32>(wdc, 0);
    wd_ws[1] = ldf<F32>(wdco, 0);
    flags[0] = f32; flags[1] = as_int;
  }
}
// embedding + h_c (direct to hB planes) + attn scalars
template<bool F32>
__device__ __forceinline__ void embed_body(
    const int* op_idx, const void* vf, const void* cs_tab, const void* tp_tab,
    const void* Wc, const void* asrc, const void* adst,
    float* x_out, short* hB_hi, short* hB_lo, float* ed_out, float* es_out,
    int rel){
  int t = threadIdx.x;
  int w = t >> 6, lane = t & 63;
  int g = rel * 4 + w;
  int b = g / NN, n = g - b * NN;
  int op = op_idx[g];
  float xv = 0.f, hacc = 0.f;
#pragma unroll
  for (int f = 0; f < 15; ++f){
    float x_f;
    if (f < 4)      x_f = ldf<F32>(cs_tab, n * 4 + f);
    else if (f < 6) x_f = ldf<F32>(tp_tab, op * 2 + (f - 4));
    else            x_f = ldf<F32>(vf, (long)g * 9 + (f - 6));
    if (lane == f) xv = x_f;
    hacc += x_f * ldf<F32>(Wc, f * COMD + lane);
  }
  if (lane < 15) x_out[g * 15 + lane] = xv;
  hB_write(hB_hi, hB_lo, b, n, lane, hacc);
  float sd = wave_sum(hacc * ldf<F32>(adst, lane));
  float ss = wave_sum(hacc * ldf<F32>(asrc, lane));
  if (lane == 0){ ed_out[g] = sd; es_out[g] = ss; }
}
__global__ void __launch_bounds__(256) k_prep(
    const void* dist, const void* adj_comp,
    const void* wdc, const void* wdco,
    const void* Wp, const void* vpd, const void* vpf, const void* bp,
    const void* Wco, const void* asrc_co, const void* adst_co,
    const int* op_idx, const void* vfeat, const void* cs_tab, const void* tp_tab,
    const void* Wc, const void* asrc_c, const void* adst_c,
    int* flags, float* wd_ws, bf16* distTb, u64* adjQc,
    short* WpB_hi, short* WpB_lo, float* wv_ws,
    short* WcoB_hi, short* WcoB_lo, float* pvco,
    float* x_ws, short* hB_hi, short* hB_lo, float* ed_c, float* es_c){
  __shared__ __attribute__((aligned(16))) char smem[SMEM_BYTES];
  int blk = blockIdx.x;
  int f32, as_int;
  sniff2(dist, adj_comp, threadIdx.x & 63, f32, as_int);
  if (blk < PB_DT){
    if (as_int) adjq_role<true >(adj_comp, adjQc, blk - PB_AQ1, smem);
    else        adjq_role<false>(adj_comp, adjQc, blk - PB_AQ1, smem);
  } else if (blk < PB_WP){
    if (f32) dist_t_role<true >(dist, distTb, blk - PB_DT, smem);
    else     dist_t_role<false>(dist, distTb, blk - PB_DT, smem);
  } else if (blk < PB_WCO){
    if (f32) wp_role<true >(Wp, vpd, vpf, WpB_hi, WpB_lo, wv_ws, blk - PB_WP);
    else     wp_role<false>(Wp, vpd, vpf, WpB_hi, WpB_lo, wv_ws, blk - PB_WP);
  } else if (blk < PB_MISC){
    if (f32) wco_role<true >(Wco, asrc_co, adst_co, WcoB_hi, WcoB_lo, pvco, blk - PB_WCO);
    else     wco_role<false>(Wco, asrc_co, adst_co, WcoB_hi, WcoB_lo, pvco, blk - PB_WCO);
  } else if (blk < PB_EMB){
    if (f32) misc_role<true >(wdc, wdco, bp, vpd, vpf, f32, as_int, flags, wd_ws, wv_ws);
    else     misc_role<false>(wdc, wdco, bp, vpd, vpf, f32, as_int, flags, wd_ws, wv_ws);
  } else {
    if (f32) embed_body<true >(op_idx, vfeat, cs_tab, tp_tab, Wc, asrc_c, adst_c,
                               x_ws, hB_hi, hB_lo, ed_c, es_c, blk - PB_EMB);
    else     embed_body<false>(op_idx, vfeat, cs_tab, tp_tab, Wc, asrc_c, adst_c,
                               x_ws, hB_hi, hB_lo, ed_c, es_c, blk - PB_EMB);
  }
}

// ---------------- masked-softmax GAT with fused epilogues ----------------
// MODE 0 (gat1): writes comp reps; fused h_co epilogue -> hB2 planes +
//   ed_o/es_o; PACKX extra x-blocks pack adj_coop -> adjQo.
// MODE 1 (gat2x): coop reps stay IN REGISTERS; fused x_p epilogue
//   (sag@Wp + bias + scf/scd dots) replaces k_xp; coop never materializes.
template<int MODE>
__device__ __forceinline__ void gat_body(
    const float* __restrict__ ed, const float* __restrict__ es,
    const float* __restrict__ wd_ws, int wd_idx, const u64* __restrict__ adjQ,
    const bf16* __restrict__ distTb,
    const short* __restrict__ hB_hi, const short* __restrict__ hB_lo,
    float* __restrict__ reps,
    const int* __restrict__ flags, const void* adj_raw, u64* adjQ_out,
    const float* __restrict__ x_ws,
    const short* __restrict__ WcoB_hi, const short* __restrict__ WcoB_lo,
    const float* __restrict__ pvco,
    short* hB2_hi, short* hB2_lo, float* ed_o, float* es_o,
    // MODE 1 extras:
    const int* __restrict__ time_idx, const int* __restrict__ op_idx,
    const void* vf, const void* time_tab, const void* cs_tab, const void* tp_tab,
    const float* __restrict__ comp,
    const short* __restrict__ WpB_hi, const short* __restrict__ WpB_lo,
    const float* __restrict__ wv_ws, const void* bp,
    float* x_p, float* scf_o, float* scd_o){
  __shared__ short pA[32 * 544] __attribute__((aligned(16)));
  __shared__ float redz[TI][4];
  __shared__ float esred[4];
  if (MODE == 0 && blockIdx.x >= GATX){
    int rel = (blockIdx.x - GATX) * NB + blockIdx.y;
    if (flags[1]) adjq_role<true >(adj_raw, adjQ_out, rel, (void*)pA);
    else          adjq_role<false>(adj_raw, adjQ_out, rel, (void*)pA);
    return;
  }
  int t = threadIdx.x;
  int wv = t >> 6, lane = t & 63;
  int b = blockIdx.y;
  int i0 = blockIdx.x * TI;
  float wd = wd_ws[wd_idx];
  int iw = i0 >> 6;
  int sb2 = (i0 & 63) >> 2;       // permuted-order uniform shift
  int j0 = t * 4;

  const u64* aq = adjQ + ((long)b * 16 + iw) * 1024 + j0;
  u64x2 wA = *(const u64x2*)&aq[0];
  u64x2 wB = *(const u64x2*)&aq[2];
  u64 wsh[4] = { wA[0] >> sb2, wA[1] >> sb2, wB[0] >> sb2, wB[1] >> sb2 };
  float4 es4 = *(const float4*)&es[(long)b * NN + j0];
  float esv[4] = {es4.x, es4.y, es4.z, es4.w};
  float esm = -1e30f;
#pragma unroll
  for (int c = 0; c < 4; ++c)
    esm = fmaxf(esm, (j0 + c < NN) ? esv[c] : -1e30f);
  esm = wave_bmax(esm);
  if (lane == 0) esred[wv] = esm;

  float ed_i[TI]; float edm = -1e30f;
#pragma unroll
  for (int ti = 0; ti < TI; ++ti){
    int i = i0 + ti;
    float ev = ed[(long)b * NN + ((i < NN) ? i : (NN - 1))];
    ed_i[ti] = ev;
    edm = fmaxf(edm, (i < NN) ? ev : -1e30f);
  }
  __syncthreads();
  float M = fmaxf(fmaxf(esred[0], esred[1]), fmaxf(esred[2], esred[3]))
            + edm + fmaxf(wd, 0.f);
  M = fmaxf(M, 0.f);   // uniform upper bound on all scores; softmax exact

  float p[TI][4];
  const bf16* dbase = distTb + j0;
#pragma unroll
  for (int ti = 0; ti < TI; ++ti){
    int i = i0 + ti;
    int ic = (i < NN) ? i : (NN - 1);
    u16x4 d4 = *(const u16x4*)&dbase[(long)ic * DSTRIDE];
    float edti = ed_i[ti];
    int psh = 16 * (ti & 3) + (ti >> 2);      // permuted bit position
#pragma unroll
    for (int c = 0; c < 4; ++c){
      float d = __uint_as_float((unsigned)d4[c] << 16);
      float v = edti + esv[c] + wd * d;
      v = fmaxf(v, 0.2f * v);                 // leaky_relu
      bool edge = (wsh[c] >> psh) & 1ull;
      float e = edge ? v : -1e30f;
      p[ti][c] = __expf(e - M);
    }
  }

  int kbw = 8 * wv + (lane >> 3);
  int qw = (lane >> 1) & 3;
  int u0 = 4 * (lane & 1);
  int wbase = kbw * 544 + qw * 136 + u0;
#pragma unroll
  for (int ti = 0; ti < TI; ++ti){
    float zs = p[ti][0] + p[ti][1] + p[ti][2] + p[ti][3];
    zs = wave_bsum(zs);
    if (lane == 0) redz[ti][wv] = zs;
    s16x4 s4 = { f2bs(p[ti][0]), f2bs(p[ti][1]), f2bs(p[ti][2]), f2bs(p[ti][3]) };
    *(s16x4*)&pA[wbase + ti * 8] = s4;
  }
  __syncthreads();

  int q = lane >> 4, m = lane & 15;
  int abase = q * 136 + m * 8;
  int ch = wv * 16 + m;
  const short* bh = hB_hi + (long)b * 65536 + ((long)q * 64 + ch) * 8;
  const short* bl = hB_lo + (long)b * 65536 + ((long)q * 64 + ch) * 8;
  f32x4 acc = {0.f, 0.f, 0.f, 0.f};
#pragma unroll
  for (int kb = 0; kb < 32; ++kb){
    s16x8 a   = *(const s16x8*)&pA[kb * 544 + abase];
    s16x8 bhi = *(const s16x8*)&bh[(long)kb * 2048];
    s16x8 blo = *(const s16x8*)&bl[(long)kb * 2048];
    acc = __builtin_amdgcn_mfma_f32_16x16x32_bf16(a, bhi, acc, 0, 0, 0);
    acc = __builtin_amdgcn_mfma_f32_16x16x32_bf16(a, blo, acc, 0, 0, 0);
  }
  float vr[4];
#pragma unroll
  for (int reg = 0; reg < 4; ++reg){
    int ti = (lane >> 4) * 4 + reg;
    float z = redz[ti][0] + redz[ti][1] + redz[ti][2] + redz[ti][3];
    float zi = (z > 0.f) ? 1.f / z : 0.f;
    float v = acc[reg] * zi;
    v = (v > 0.f) ? v : expm1f(v);
    vr[reg] = v;
    if (MODE == 0){
      int ch2 = wv * 16 + (lane & 15);
      if (i0 + ti < NN)
        reps[((long)b * NN + i0 + ti) * COMD + ch2] = v;
    }
  }

  if (MODE == 0){
    // ---- fused h_co epilogue (replaces k_hco), overlaying pA's LDS ----
    __syncthreads();                 // all pA reads done; safe to overwrite
    float* cx = (float*)pA;          // [16][80] fp32, 5120 B
    short* cA_hi = pA + 2560;        // 3*16*40 shorts
    short* cA_lo = pA + 2560 + 1920;
    {
      int ch2 = wv * 16 + (lane & 15);
#pragma unroll
      for (int reg = 0; reg < 4; ++reg){
        int row = (lane >> 4) * 4 + reg;
        cx[row * 80 + 15 + ch2] = vr[reg];
      }
    }
    for (int idx = t; idx < 16 * 15; idx += 256){
      int nl = idx / 15, f = idx - nl * 15;
      int i = i0 + nl; int ic = (i < NN) ? i : (NN - 1);
      cx[nl * 80 + f] = x_ws[((long)b * NN + ic) * 15 + f];
    }
    __syncthreads();
    {
      int node = t >> 4, sub = t & 15;
      float dd = 0.f, ss = 0.f;
      for (int f = sub; f < 79; f += 16){
        float c = cx[node * 80 + f];
        dd += c * pvco[f];
        ss += c * pvco[96 + f];
      }
#pragma unroll
      for (int o = 8; o > 0; o >>= 1){
        dd += __shfl_xor(dd, o, 64);
        ss += __shfl_xor(ss, o, 64);
      }
      if (sub == 0 && i0 + node < NN){
        ed_o[(long)b * NN + i0 + node] = dd;
        es_o[(long)b * NN + i0 + node] = ss;
      }
    }
    for (int idx = t; idx < 16 * 96; idx += 256){
      int mm = idx / 96, k = idx - mm * 96;
      float v = (k < 79) ? cx[mm * 80 + k] : 0.f;
      int kb = k >> 5, qq = (k >> 3) & 3, u = k & 7;
      short hi, lo; split_bf(v, hi, lo);
      int off = (kb * 16 + mm) * 40 + qq * 8 + u;
      cA_hi[off] = hi; cA_lo[off] = lo;
    }
    __syncthreads();
    {
      int q2 = lane >> 4, m2 = lane & 15;
      int ch3 = wv * 16 + m2;
      f32x4 a2 = {0.f, 0.f, 0.f, 0.f};
#pragma unroll
      for (int kb = 0; kb < 3; ++kb){
        int aoff = (kb * 16 + m2) * 40 + q2 * 8;
        s16x8 a_hi = *(const s16x8*)&cA_hi[aoff];
        s16x8 a_lo = *(const s16x8*)&cA_lo[aoff];
        long boff = (((long)(kb * 4 + q2)) * 64 + ch3) * 8;
        s16x8 b_hi = *(const s16x8*)&WcoB_hi[boff];
        s16x8 b_lo = *(const s16x8*)&WcoB_lo[boff];
        a2 = __builtin_amdgcn_mfma_f32_16x16x32_bf16(a_hi, b_hi, a2, 0, 0, 0);
        a2 = __builtin_amdgcn_mfma_f32_16x16x32_bf16(a_hi, b_lo, a2, 0, 0, 0);
        a2 = __builtin_amdgcn_mfma_f32_16x16x32_bf16(a_lo, b_hi, a2, 0, 0, 0);
      }
#pragma unroll
      for (int reg = 0; reg < 4; ++reg){
        int row = (lane >> 4) * 4 + reg;
        int n2 = i0 + row;                 // n<1024 slots exist; tail unread
        hB_write(hB2_hi, hB2_lo, b, n2, ch3, a2[reg]);
      }
    }
  } else {
    // ---- fused x_p epilogue (replaces k_xp), overlaying pA's LDS ----
    __syncthreads();                 // all pA reads done; safe to overwrite
    float* sagF = (float*)pA;        // [16][148] fp32 = 9472 B
    short* sgA_hi = pA + 4736;       // 5*16*40 shorts = 6400 B
    short* sgA_lo = pA + 7936;       // 5*16*40 shorts
    int f32 = flags[0];
    {
      int ch2 = wv * 16 + (lane & 15);
#pragma unroll
      for (int reg = 0; reg < 4; ++reg){
        int row = (lane >> 4) * 4 + reg;
        sagF[row * 148 + 83 + ch2] = vr[reg];   // coop from registers
      }
    }
    for (int idx = t; idx < 16 * 83; idx += 256){
      int nl = idx / 83, f = idx - nl * 83;
      int n = i0 + nl; int ic = (n < NN) ? n : (NN - 1);
      long g = (long)b * NN + ic;
      float v;
      if (f < 4)       v = ldr(time_tab, (long)time_idx[g] * 4 + f, f32);
      else if (f < 8)  v = ldr(cs_tab, ic * 4 + (f - 4), f32);
      else if (f < 10) v = ldr(tp_tab, (long)op_idx[g] * 2 + (f - 8), f32);
      else if (f < 19) v = ldr(vf, g * 9 + (f - 10), f32);
      else             v = comp[g * COMD + (f - 19)];
      sagF[nl * 148 + f] = v;
    }
    __syncthreads();
    for (int idx = t; idx < 16 * 160; idx += 256){
      int mm = idx / 160, k = idx - mm * 160;
      float v = (k < 147) ? sagF[mm * 148 + k] : 0.f;
      int kb = k >> 5, qq = (k >> 3) & 3, u = k & 7;
      short hi, lo; split_bf(v, hi, lo);
      int off = (kb * 16 + mm) * 40 + qq * 8 + u;
      sgA_hi[off] = hi; sgA_lo[off] = lo;
    }
    {
      int node = t >> 4, sub = t & 15;
      float ad = 0.f, af = 0.f;
      for (int f = sub; f < 147; f += 16){
        float s = sagF[node * 148 + f];
        ad += s * wv_ws[f];
        af += s * wv_ws[160 + f];
      }
#pragma unroll
      for (int o = 8; o > 0; o >>= 1){
        ad += __shfl_xor(ad, o, 64);
        af += __shfl_xor(af, o, 64);
      }
      if (sub == 0 && i0 + node < NN){
        scd_o[(long)b * NN + i0 + node] = ad + wv_ws[320];
        scf_o[(long)b * NN + i0 + node] = af + wv_ws[321];
      }
    }
    __syncthreads();
    int Ag = lane >> 4, Am = lane & 15;
    f32x4 acc2[4] = {{0,0,0,0},{0,0,0,0},{0,0,0,0},{0,0,0,0}};
#pragma unroll
    for (int kb = 0; kb < 5; ++kb){
      int aoff = (kb * 16 + Am) * 40 + Ag * 8;
      s16x8 a_hi = *(const s16x8*)&sgA_hi[aoff];
      s16x8 a_lo = *(const s16x8*)&sgA_lo[aoff];
#pragma unroll
      for (int ct = 0; ct < 4; ++ct){
        int ch3 = wv * 64 + ct * 16 + Am;
        long boff = (((long)(kb * 4 + Ag)) * 256 + ch3) * 8;
        s16x8 b_hi = *(const s16x8*)&WpB_hi[boff];
        s16x8 b_lo = *(const s16x8*)&WpB_lo[boff];
        acc2[ct] = __builtin_amdgcn_mfma_f32_16x16x32_bf16(a_hi, b_hi, acc2[ct], 0, 0, 0);
        acc2[ct] = __builtin_amdgcn_mfma_f32_16x16x32_bf16(a_hi, b_lo, acc2[ct], 0, 0, 0);
        acc2[ct] = __builtin_amdgcn_mfma_f32_16x16x32_bf16(a_lo, b_hi, acc2[ct], 0, 0, 0);
      }
    }
#pragma unroll
    for (int ct = 0; ct < 4; ++ct){
      int ch3 = wv * 64 + ct * 16 + (lane & 15);
      float bb = ldr(bp, ch3, f32);
#pragma unroll
      for (int reg = 0; reg < 4; ++reg){
        int row = (lane >> 4) * 4 + reg;
        if (i0 + row < NN)
          x_p[((long)b * NN + i0 + row) * HIDD + ch3] = acc2[ct][reg] + bb;
      }
    }
  }
}
__global__ void __launch_bounds__(256) k_gat1(
    const float* ed, const float* es, const float* wd_ws, const u64* adjQ,
    const bf16* distTb, const short* hB_hi, const short* hB_lo, float* reps,
    const int* flags, const void* adj_raw, u64* adjQ_out,
    const float* x_ws, const short* WcoB_hi, const short* WcoB_lo,
    const float* pvco, short* hB2_hi, short* hB2_lo, float* ed_o, float* es_o){
  gat_body<0>(ed, es, wd_ws, 0, adjQ, distTb, hB_hi, hB_lo, reps,
              flags, adj_raw, adjQ_out, x_ws, WcoB_hi, WcoB_lo, pvco,
              hB2_hi, hB2_lo, ed_o, es_o,
              nullptr, nullptr, nullptr, nullptr, nullptr, nullptr,
              nullptr, nullptr, nullptr, nullptr, nullptr,
              nullptr, nullptr, nullptr);
}
__global__ void __launch_bounds__(256) k_gat2x(
    const float* ed, const float* es, const float* wd_ws, const u64* adjQ,
    const bf16* distTb, const short* hB_hi, const short* hB_lo,
    const int* flags,
    const int* time_idx, const int* op_idx, const void* vf,
    const void* time_tab, const void* cs_tab, const void* tp_tab,
    const float* comp, const short* WpB_hi, const short* WpB_lo,
    const float* wv_ws, const void* bp,
    float* x_p, float* scf, float* scd){
  gat_body<1>(ed, es, wd_ws, 1, adjQ, distTb, hB_hi, hB_lo, nullptr,
              flags, nullptr, nullptr, nullptr, nullptr, nullptr, nullptr,
              nullptr, nullptr, nullptr, nullptr,
              time_idx, op_idx, vf, time_tab, cs_tab, tp_tab,
              comp, WpB_hi, WpB_lo, wv_ws, bp, x_p, scf, scd);
}

// ---------------- top-k weights: one wave per (b,pool) ----------------
template<bool BINT>
__device__ __forceinline__ void topk_body(
    const float* scf, const float* scd, const void* mark, float* wls){
  int lane = threadIdx.x;
  int b = blockIdx.x, pool = blockIdx.y;
  const float* sc = (pool == 0) ? scf : scd;
  float v[16]; unsigned key[16];
  float m0 = -INFINITY;
#pragma unroll
  for (int r = 0; r < 16; ++r){
    int n = r * 64 + lane;
    float s = (n < NN) ? sc[b * NN + n] : -INFINITY;
    v[r] = s;
    m0 = fmaxf(m0, s);
  }
  m0 = wave_bmax(m0);
  float m1 = -INFINITY;
#pragma unroll
  for (int r = 0; r < 16; ++r){
    int n = r * 64 + lane;
    bool valid = false;
    if (n < NN){
      bool mk = ldb<BINT>(mark, b * NN + n);
      valid = (pool == 0) ? !mk : mk;
    }
    v[r] = valid ? (v[r] - m0) : -1e8f;
    key[r] = fkey(v[r]);
    if (n < NN) m1 = fmaxf(m1, v[r]);
  }
  m1 = wave_bmax(m1);

  unsigned lo = 0u, hi = 0xFFFFFFFFu;
  while (lo < hi){
    unsigned mid = lo + ((hi - lo) >> 1) + 1u;
    int c = 0;
#pragma unroll
    for (int r = 0; r < 16; ++r) c += (key[r] >= mid) ? 1 : 0;
    c = wave_bsum_i(c);
    if (c >= KSEL) lo = mid; else hi = mid - 1u;
  }

  float p[16];
  float ls = 0.f;
#pragma unroll
  for (int r = 0; r < 16; ++r){
    int n = r * 64 + lane;
    float pp = (n < NN && key[r] >= lo) ? __expf(v[r] - m1) : 0.f;
    p[r] = pp;
    ls += pp;
  }
  ls = wave_bsum(ls);
  float zinv = (ls > 0.f) ? 1.f / ls : 0.f;
  float* w_out = wls + ((long)b * 2 + pool) * 1024;
#pragma unroll
  for (int r = 0; r < 16; ++r){
    int n = r * 64 + lane;
    if (n < NN) w_out[n] = p[r] * zinv;
  }
}
__global__ void k_topk(const int* flags, const float* scf, const float* scd,
                       const void* mark, float* wls){
  if (flags[1]) topk_body<true >(scf, scd, mark, wls);
  else          topk_body<false>(scf, scd, mark, wls);
}

// ---------------- gated partial sums ----------------
__global__ void __launch_bounds__(256) k_psum(
    const float* __restrict__ wls, const float* __restrict__ x_p,
    float* __restrict__ part){
  __shared__ float wf[ROWS], wdd[ROWS];
  int t = threadIdx.x;
  int b = blockIdx.x, z = blockIdx.y;
  int n0 = z * ROWS;
  int ns = min(ROWS, NN - n0);
  if (t < ns){
    wf[t]  = wls[((long)b * 2 + 0) * 1024 + n0 + t];
    wdd[t] = wls[((long)b * 2 + 1) * 1024 + n0 + t];
  }
  __syncthreads();
  float sf = 0.f, mf = -INFINITY, sd = 0.f, md = -INFINITY;
  const float* xb = x_p + ((long)b * NN + n0) * HIDD + t;
  for (int k = 0; k < ns; ++k){
    float xv = xb[(long)k * HIDD];
    float gf = wf[k] * xv;
    float gd = wdd[k] * xv;
    sf += gf; mf = fmaxf(mf, gf);
    sd += gd; md = fmaxf(md, gd);
  }
  long pb = (((long)b * NSPL + z) * 4) * HIDD + t;
  part[pb + 0 * HIDD] = sf;
  part[pb + 1 * HIDD] = mf;
  part[pb + 2 * HIDD] = sd;
  part[pb + 3 * HIDD] = md;
}

// ---------------- final reduce ----------------
template<bool F32>
__device__ __forceinline__ void pfin_body(const float* part, void* out){
  int t = threadIdx.x;
  int b = blockIdx.x;
  float sf = 0.f, mf = -INFINITY, sd = 0.f, md = -INFINITY;
#pragma unroll
  for (int z = 0; z < NSPL; ++z){
    long pb = (((long)b * NSPL + z) * 4) * HIDD + t;
    sf += part[pb + 0 * HIDD];
    mf = fmaxf(mf, part[pb + 1 * HIDD]);
    sd += part[pb + 2 * HIDD];
    md = fmaxf(md, part[pb + 3 * HIDD]);
  }
  long ob = (long)b * 1024;
  if (F32){
    ((float*)out)[ob + t] = sf;
    ((float*)out)[ob + 256 + t] = mf;
    ((float*)out)[ob + 512 + t] = sd;
    ((float*)out)[ob + 768 + t] = md;
  } else {
    ((bf16*)out)[ob + t] = __float2bfloat16(sf);
    ((bf16*)out)[ob + 256 + t] = __float2bfloat16(mf);
    ((bf16*)out)[ob + 512 + t] = __float2bfloat16(sd);
    ((bf16*)out)[ob + 768 + t] = __float2bfloat16(md);
  }
}
__global__ void k_pfin(const int* flags, const float* part, void* out){
  if (flags[0]) pfin_body<true >(part, out);
  else          pfin_body<false>(part, out);
}

extern "C" void kernel_launch(void* const* d_in, const int* in_sizes, int n_in,
                              void* d_out, int out_size, void* d_ws, size_t ws_size,
                              hipStream_t stream){
  const int*  time_idx = (const int*)d_in[0];
  const int*  op_idx   = (const int*)d_in[1];
  const void* vfeat    = d_in[2];
  const void* dpcs     = d_in[3];
  const void* adj_comp = d_in[4];
  const void* adj_coop = d_in[5];
  const void* dist     = d_in[6];
  const void* time_tab = d_in[7];
  const void* tp_tab   = d_in[8];
  const void* cs_tab   = d_in[9];
  const void* Wc       = d_in[10];
  const void* asrc_c   = d_in[11];
  const void* adst_c   = d_in[12];
  const void* wd_c     = d_in[13];
  const void* Wco      = d_in[14];
  const void* asrc_co  = d_in[15];
  const void* adst_co  = d_in[16];
  const void* wd_co    = d_in[17];
  const void* Wp       = d_in[18];
  const void* bp       = d_in[19];
  const void* vpd      = d_in[20];
  const void* vpf      = d_in[21];

  char* ws = (char*)d_ws;
  size_t o = 0;
  auto alloc = [&](size_t bytes)->char*{
    char* p = ws + o; o = (o + bytes + 255) & ~(size_t)255; return p;
  };
  int*   flags   = (int*)alloc(16);
  float* wd_ws   = (float*)alloc(8);
  bf16*  distTb  = (bf16*)alloc((size_t)NN * DSTRIDE * 2);
  u64*   adjQc   = (u64*)alloc((size_t)NB * 16 * 1024 * 8);
  u64*   adjQo   = (u64*)alloc((size_t)NB * 16 * 1024 * 8);
  float* x_ws    = (float*)alloc((size_t)NB * NN * 15 * 4);
  float* comp    = (float*)alloc((size_t)NB * NN * COMD * 4);
  short* hB_hi   = (short*)alloc((size_t)NB * 65536 * 2);
  short* hB_lo   = (short*)alloc((size_t)NB * 65536 * 2);
  short* hB2_hi  = (short*)alloc((size_t)NB * 65536 * 2);
  short* hB2_lo  = (short*)alloc((size_t)NB * 65536 * 2);
  short* WpB_hi  = (short*)alloc((size_t)5 * 4 * 256 * 8 * 2);
  short* WpB_lo  = (short*)alloc((size_t)5 * 4 * 256 * 8 * 2);
  short* WcoB_hi = (short*)alloc((size_t)3 * 4 * 64 * 8 * 2);
  short* WcoB_lo = (short*)alloc((size_t)3 * 4 * 64 * 8 * 2);
  float* wv_ws   = (float*)alloc(322 * 4);
  float* pvco    = (float*)alloc(192 * 4);
  float* ed_c    = (float*)alloc((size_t)NB * NN * 4 + 256);
  float* es_c    = (float*)alloc((size_t)NB * NN * 4 + 256);
  float* ed_o    = (float*)alloc((size_t)NB * NN * 4 + 256);
  float* es_o    = (float*)alloc((size_t)NB * NN * 4 + 256);
  float* scf     = (float*)alloc((size_t)NB * NN * 4);
  float* scd     = (float*)alloc((size_t)NB * NN * 4);
  float* wls     = (float*)alloc((size_t)NB * 2 * 1024 * 4);
  float* part    = (float*)alloc((size_t)NB * NSPL * 4 * HIDD * 4);
  float* x_p     = (float*)alloc((size_t)NB * NN * HIDD * 4);

  k_prep<<<dim3(PB_N), dim3(256), 0, stream>>>(
      dist, adj_comp, wd_c, wd_co, Wp, vpd, vpf, bp,
      Wco, asrc_co, adst_co,
      op_idx, vfeat, cs_tab, tp_tab, Wc, asrc_c, adst_c,
      flags, wd_ws, distTb, adjQc, WpB_hi, WpB_lo, wv_ws,
      WcoB_hi, WcoB_lo, pvco,
      x_ws, hB_hi, hB_lo, ed_c, es_c);
  // gat#1: comp GAT + fused h_co epilogue + adjQo pack blocks (overlapped)
  k_gat1<<<dim3(GATX + PACKX, NB), dim3(256), 0, stream>>>(
      ed_c, es_c, wd_ws, adjQc, distTb, hB_hi, hB_lo, comp,
      flags, adj_coop, adjQo,
      x_ws, WcoB_hi, WcoB_lo, pvco, hB2_hi, hB2_lo, ed_o, es_o);
  // gat#2: coop GAT + fused x_p/sag epilogue (coop stays in registers)
  k_gat2x<<<dim3(GATX, NB), dim3(256), 0, stream>>>(
      ed_o, es_o, wd_ws, adjQo, distTb, hB2_hi, hB2_lo,
      flags, time_idx, op_idx, vfeat, time_tab, cs_tab, tp_tab,
      comp, WpB_hi, WpB_lo, wv_ws, bp, x_p, scf, scd);
  // tail: kernel boundaries provide the ordering
  k_topk<<<dim3(NB, 2), dim3(64), 0, stream>>>(flags, scf, scd, dpcs, wls);
  k_psum<<<dim3(NB, NSPL), dim3(256), 0, stream>>>(wls, x_p, part);
  k_pfin<<<dim3(NB), dim3(256), 0, stream>>>(flags, part, d_out);
}